// Round 1
// baseline (513.051 us; speedup 1.0000x reference)
//
#include <hip/hip_runtime.h>

// Problem constants
#define TPB 256          // threads per block (4 waves)
#define BPB 64           // batches per block (lane = local batch)
#define NQ 25
#define ND 9
#define XWORDS (BPB * NQ * ND)   // 14400 floats staged per block
#define X4 (XWORDS / 4)          // 3600 float4
#define KV_OFF 8000              // uint32 word offset of V region in LDS
#define SMEM_WORDS 16000         // 64000 bytes static LDS (< 64 KiB limit)
#define SOFTMAX_SHIFT 40.0f      // constant shift: s <= ~110 << 40+88, s_qq >= 0 => l >= e^-40

typedef _Float16 h2 __attribute__((ext_vector_type(2)));
typedef float f4 __attribute__((ext_vector_type(4)));

__device__ __forceinline__ float dot2acc(h2 a, h2 b, float c) {
#if __has_builtin(__builtin_amdgcn_fdot2)
    return __builtin_amdgcn_fdot2(a, b, c, false);
#else
    return c + (float)a[0] * (float)b[0] + (float)a[1] * (float)b[1];
#endif
}

__global__ __launch_bounds__(TPB, 2) void attn_fused(
    const float* __restrict__ x,
    const float* __restrict__ Wjk, const float* __restrict__ bjk,
    const float* __restrict__ Wok, const float* __restrict__ bok,
    const float* __restrict__ Wgk, const float* __restrict__ bgk,
    const float* __restrict__ Wbk, const float* __restrict__ bbk,
    const float* __restrict__ Wjv, const float* __restrict__ bjv,
    const float* __restrict__ Wov, const float* __restrict__ bov,
    const float* __restrict__ Wgv, const float* __restrict__ bgv,
    const float* __restrict__ Wbv, const float* __restrict__ bbv,
    const float* __restrict__ ln_g, const float* __restrict__ ln_b,
    float* __restrict__ out)
{
    __shared__ unsigned int sm[SMEM_WORDS];

    const int tid  = threadIdx.x;
    const int lane = tid & 63;                                   // local batch
    const int w    = __builtin_amdgcn_readfirstlane(tid >> 6);   // wave id (uniform)
    const long base = (long)blockIdx.x * XWORDS;

    // ---- phase 1: coalesced stage of x chunk into LDS ----
    {
        const f4* src = (const f4*)(x + base);
        f4* dst = (f4*)sm;
        #pragma unroll
        for (int i = 0; i < 15; ++i) {
            int idx = tid + i * TPB;
            if (idx < X4) dst[idx] = src[idx];
        }
    }
    __syncthreads();

    // wave w owns queries [qs, qs+qc): {0-6, 7-12, 13-18, 19-24}
    const int qs = (w == 0) ? 0 : 6 * w + 1;
    const int qc = (w == 0) ? 7 : 6;

    // ---- phase 2: read my x rows into registers (conflict-free: stride 225 % 32 == 1) ----
    float xr[7][9];
    #pragma unroll
    for (int j = 0; j < 7; ++j) {
        if (j < qc) {
            const float* xsrc = (const float*)sm + lane * (NQ * ND) + (qs + j) * ND;
            #pragma unroll
            for (int d = 0; d < ND; ++d) xr[j][d] = xsrc[d];
        }
    }
    __syncthreads();   // all x reads done before K/V overwrite the region

    // ---- phase 3: K,V projections (SGPR weights), pack fp16, write to LDS ----
    // LDS layout (half2-SoA): K word = hp*1600 + q*64 + lane ; V at +KV_OFF.
    h2 kreg[7][5];
    #pragma unroll
    for (int j = 0; j < 7; ++j) {
        if (j < qc) {
            const int q = qs + j;                                  // wave-uniform
            const int seg = (q >= 3) + (q >= 13) + (q >= 23);      // wave-uniform
            const float* Wk = (seg == 0) ? Wjk : (seg == 1) ? Wok : (seg == 2) ? Wgk : Wbk;
            const float* bk = (seg == 0) ? bjk : (seg == 1) ? bok : (seg == 2) ? bgk : bbk;
            const float* Wv = (seg == 0) ? Wjv : (seg == 1) ? Wov : (seg == 2) ? Wgv : Wbv;
            const float* bv = (seg == 0) ? bjv : (seg == 1) ? bov : (seg == 2) ? bgv : bbv;

            float kk[9], vv[9];
            #pragma unroll
            for (int o = 0; o < ND; ++o) {
                float ak = bk[o];
                float av = bv[o];
                #pragma unroll
                for (int i = 0; i < ND; ++i) {
                    ak += Wk[o * ND + i] * xr[j][i];
                    av += Wv[o * ND + i] * xr[j][i];
                }
                kk[o] = ak; vv[o] = av;
            }
            #pragma unroll
            for (int hp = 0; hp < 5; ++hp) {
                float k0 = kk[2 * hp], k1 = (hp < 4) ? kk[2 * hp + 1] : 0.0f;
                float v0 = vv[2 * hp], v1 = (hp < 4) ? vv[2 * hp + 1] : 0.0f;
                h2 kh; kh[0] = (_Float16)k0; kh[1] = (_Float16)k1;
                h2 vh; vh[0] = (_Float16)v0; vh[1] = (_Float16)v1;
                kreg[j][hp] = kh;
                sm[hp * 1600 + q * 64 + lane]          = __builtin_bit_cast(unsigned int, kh);
                sm[KV_OFF + hp * 1600 + q * 64 + lane] = __builtin_bit_cast(unsigned int, vh);
            }
        }
    }
    __syncthreads();

    // ---- phase 4: fused scores + shifted-softmax + PV accumulation ----
    float res[7][9];
    float lsum[7];
    #pragma unroll
    for (int j = 0; j < 7; ++j) {
        lsum[j] = 0.0f;
        #pragma unroll
        for (int d = 0; d < ND; ++d) res[j][d] = 0.0f;
    }

    #pragma unroll 1
    for (int k = 0; k < NQ; ++k) {
        h2 kh[5], vh[5];
        #pragma unroll
        for (int hp = 0; hp < 5; ++hp) {
            kh[hp] = __builtin_bit_cast(h2, sm[hp * 1600 + k * 64 + lane]);
            vh[hp] = __builtin_bit_cast(h2, sm[KV_OFF + hp * 1600 + k * 64 + lane]);
        }
        float vf[9];
        #pragma unroll
        for (int hp = 0; hp < 4; ++hp) {
            vf[2 * hp]     = (float)vh[hp][0];
            vf[2 * hp + 1] = (float)vh[hp][1];
        }
        vf[8] = (float)vh[4][0];

        #pragma unroll
        for (int j = 0; j < 7; ++j) {
            if (j < qc) {
                float s = 0.0f;
                #pragma unroll
                for (int hp = 0; hp < 5; ++hp) s = dot2acc(kreg[j][hp], kh[hp], s);
                float e = __expf(s - SOFTMAX_SHIFT);
                lsum[j] += e;
                #pragma unroll
                for (int d = 0; d < ND; ++d) res[j][d] += e * vf[d];
            }
        }
    }
    __syncthreads();   // all K/V reads done before y overwrites the region

    // ---- phase 5: residual + LayerNorm, write y rows to LDS ----
    float g[9], bb[9];
    #pragma unroll
    for (int d = 0; d < ND; ++d) { g[d] = ln_g[d]; bb[d] = ln_b[d]; }

    #pragma unroll
    for (int j = 0; j < 7; ++j) {
        if (j < qc) {
            float rl = __builtin_amdgcn_rcpf(lsum[j]);
            float y[9];
            float s = 0.0f;
            #pragma unroll
            for (int d = 0; d < ND; ++d) {
                y[d] = xr[j][d] + res[j][d] * rl;
                s += y[d];
            }
            float mu = s * (1.0f / 9.0f);
            float var = 0.0f;
            #pragma unroll
            for (int d = 0; d < ND; ++d) {
                float t = y[d] - mu;
                var += t * t;
            }
            float rs = __builtin_amdgcn_rsqf(var * (1.0f / 9.0f) + 1e-5f);
            float* ydst = (float*)sm + lane * (NQ * ND) + (qs + j) * ND;
            #pragma unroll
            for (int d = 0; d < ND; ++d) ydst[d] = (y[d] - mu) * rs * g[d] + bb[d];
        }
    }
    __syncthreads();

    // ---- phase 6: coalesced store of y chunk ----
    {
        const f4* srcs = (const f4*)sm;
        f4* dstg = (f4*)(out + base);
        #pragma unroll
        for (int i = 0; i < 15; ++i) {
            int idx = tid + i * TPB;
            if (idx < X4) dstg[idx] = srcs[idx];
        }
    }
}

extern "C" void kernel_launch(void* const* d_in, const int* in_sizes, int n_in,
                              void* d_out, int out_size, void* d_ws, size_t ws_size,
                              hipStream_t stream) {
    const float* x   = (const float*)d_in[0];
    const float* Wjk = (const float*)d_in[1];
    const float* bjk = (const float*)d_in[2];
    const float* Wok = (const float*)d_in[3];
    const float* bok = (const float*)d_in[4];
    const float* Wgk = (const float*)d_in[5];
    const float* bgk = (const float*)d_in[6];
    const float* Wbk = (const float*)d_in[7];
    const float* bbk = (const float*)d_in[8];
    const float* Wjv = (const float*)d_in[9];
    const float* bjv = (const float*)d_in[10];
    const float* Wov = (const float*)d_in[11];
    const float* bov = (const float*)d_in[12];
    const float* Wgv = (const float*)d_in[13];
    const float* bgv = (const float*)d_in[14];
    const float* Wbv = (const float*)d_in[15];
    const float* bbv = (const float*)d_in[16];
    const float* lng = (const float*)d_in[17];
    const float* lnb = (const float*)d_in[18];
    float* out = (float*)d_out;

    const int nbatch = in_sizes[0] / (NQ * ND);      // 262144
    const int nblocks = nbatch / BPB;                // 4096

    hipLaunchKernelGGL(attn_fused, dim3(nblocks), dim3(TPB), 0, stream,
                       x, Wjk, bjk, Wok, bok, Wgk, bgk, Wbk, bbk,
                       Wjv, bjv, Wov, bov, Wgv, bgv, Wbv, bbv, lng, lnb, out);
}

// Round 2
// 508.015 us; speedup vs baseline: 1.0099x; 1.0099x over previous
//
#include <hip/hip_runtime.h>

// Problem constants
#define TPB 512          // threads per block (8 waves share one 64-batch group)
#define BPB 64           // batches per block (lane = local batch)
#define NQ 25
#define ND 9
#define XWORDS (BPB * NQ * ND)   // 14400 floats staged per block
#define X4 (XWORDS / 4)          // 3600 float4
#define KV_OFF 8000              // uint32 word offset of V region in LDS
#define SMEM_WORDS 16000         // 64000 bytes static LDS (< 64 KiB limit)
#define LOG2E 1.44269504088896340736f
#define C2 (40.0f * LOG2E)       // softmax shift, log2 domain: s<=~110 << 40+88; s_qq>=0 => l>=2^-57.7

typedef _Float16 h2 __attribute__((ext_vector_type(2)));
typedef float f2 __attribute__((ext_vector_type(2)));
typedef float f4 __attribute__((ext_vector_type(4)));

__device__ __forceinline__ float dot2acc(h2 a, h2 b, float c) {
#if __has_builtin(__builtin_amdgcn_fdot2)
    return __builtin_amdgcn_fdot2(a, b, c, false);
#else
    return c + (float)a[0] * (float)b[0] + (float)a[1] * (float)b[1];
#endif
}

__device__ __forceinline__ float fast_exp2(float x) {
#if __has_builtin(__builtin_amdgcn_exp2f)
    return __builtin_amdgcn_exp2f(x);
#else
    return exp2f(x);
#endif
}

// 8 waves: wave 0 owns q 0-3, wave w>=1 owns q [3w+1, 3w+4)
__global__ __launch_bounds__(TPB, 4) void attn_fused(
    const float* __restrict__ x,
    const float* __restrict__ Wjk, const float* __restrict__ bjk,
    const float* __restrict__ Wok, const float* __restrict__ bok,
    const float* __restrict__ Wgk, const float* __restrict__ bgk,
    const float* __restrict__ Wbk, const float* __restrict__ bbk,
    const float* __restrict__ Wjv, const float* __restrict__ bjv,
    const float* __restrict__ Wov, const float* __restrict__ bov,
    const float* __restrict__ Wgv, const float* __restrict__ bgv,
    const float* __restrict__ Wbv, const float* __restrict__ bbv,
    const float* __restrict__ ln_g, const float* __restrict__ ln_b,
    float* __restrict__ out)
{
    __shared__ alignas(16) unsigned int sm[SMEM_WORDS];

    const int tid  = threadIdx.x;
    const int lane = tid & 63;                                   // local batch
    const int w    = __builtin_amdgcn_readfirstlane(tid >> 6);   // wave id (uniform)
    const long base = (long)blockIdx.x * XWORDS;

    // ---- phase 1: coalesced stage of x chunk into LDS ----
    {
        const f4* src = (const f4*)(x + base);
        f4* dst = (f4*)sm;
        #pragma unroll
        for (int i = 0; i < 8; ++i) {
            int idx = tid + i * TPB;
            if (idx < X4) dst[idx] = src[idx];
        }
    }
    __syncthreads();

    const int qs = (w == 0) ? 0 : 3 * w + 1;
    const int qc = (w == 0) ? 4 : 3;

    // ---- phase 2: read my x rows (stride 225 % 32 == 1 -> conflict-free) ----
    float xr[4][9];
    #pragma unroll
    for (int j = 0; j < 4; ++j) {
        if (j < qc) {
            const float* xsrc = (const float*)sm + lane * (NQ * ND) + (qs + j) * ND;
            #pragma unroll
            for (int d = 0; d < ND; ++d) xr[j][d] = xsrc[d];
        }
    }
    __syncthreads();   // all x reads done before K/V overwrite the region

    // ---- phase 3: K,V projections (SGPR weights), pack fp16, write LDS ----
    // LDS (half2-SoA): K word = hp*1600 + q*64 + lane ; V at +KV_OFF.
    // kreg keeps the q-side operand PRE-SCALED by log2(e) (applied in fp32).
    h2 kreg[4][5];
    #pragma unroll
    for (int j = 0; j < 4; ++j) {
        if (j < qc) {
            const int q = qs + j;                                  // wave-uniform
            const int seg = (q >= 3) + (q >= 13) + (q >= 23);      // wave-uniform
            const float* Wk = (seg == 0) ? Wjk : (seg == 1) ? Wok : (seg == 2) ? Wgk : Wbk;
            const float* bk = (seg == 0) ? bjk : (seg == 1) ? bok : (seg == 2) ? bgk : bbk;
            const float* Wv = (seg == 0) ? Wjv : (seg == 1) ? Wov : (seg == 2) ? Wgv : Wbv;
            const float* bv = (seg == 0) ? bjv : (seg == 1) ? bov : (seg == 2) ? bgv : bbv;

            float kk[9], vv[9];
            #pragma unroll
            for (int o = 0; o < ND; ++o) {
                float ak = bk[o];
                float av = bv[o];
                #pragma unroll
                for (int i = 0; i < ND; ++i) {
                    ak += Wk[o * ND + i] * xr[j][i];
                    av += Wv[o * ND + i] * xr[j][i];
                }
                kk[o] = ak; vv[o] = av;
            }
            #pragma unroll
            for (int hp = 0; hp < 5; ++hp) {
                float k0 = kk[2 * hp], k1 = (hp < 4) ? kk[2 * hp + 1] : 0.0f;
                float v0 = vv[2 * hp], v1 = (hp < 4) ? vv[2 * hp + 1] : 0.0f;
                h2 kh; kh[0] = (_Float16)k0; kh[1] = (_Float16)k1;
                h2 vh; vh[0] = (_Float16)v0; vh[1] = (_Float16)v1;
                h2 ks; ks[0] = (_Float16)(k0 * LOG2E); ks[1] = (_Float16)(k1 * LOG2E);
                kreg[j][hp] = ks;
                sm[hp * 1600 + q * 64 + lane]          = __builtin_bit_cast(unsigned int, kh);
                sm[KV_OFF + hp * 1600 + q * 64 + lane] = __builtin_bit_cast(unsigned int, vh);
            }
        }
    }
    __syncthreads();

    // ---- phase 4: fused scores + shifted-softmax(exp2 domain) + PV ----
    f2 res2[4][5];
    float lsum[4];
    #pragma unroll
    for (int j = 0; j < 4; ++j) {
        lsum[j] = 0.0f;
        #pragma unroll
        for (int hp = 0; hp < 5; ++hp) { res2[j][hp][0] = 0.0f; res2[j][hp][1] = 0.0f; }
    }

    #pragma unroll 1
    for (int k = 0; k < NQ; ++k) {
        h2 kh[5], vh[5];
        #pragma unroll
        for (int hp = 0; hp < 5; ++hp) {
            kh[hp] = __builtin_bit_cast(h2, sm[hp * 1600 + k * 64 + lane]);
            vh[hp] = __builtin_bit_cast(h2, sm[KV_OFF + hp * 1600 + k * 64 + lane]);
        }
        f2 vf2[5];
        #pragma unroll
        for (int hp = 0; hp < 5; ++hp) {
            vf2[hp][0] = (float)vh[hp][0];
            vf2[hp][1] = (float)vh[hp][1];
        }

        #pragma unroll
        for (int j = 0; j < 4; ++j) {
            if (j < qc) {
                float s = -C2;                       // shift folded into dot init
                #pragma unroll
                for (int hp = 0; hp < 5; ++hp) s = dot2acc(kreg[j][hp], kh[hp], s);
                float e = fast_exp2(s);              // exp(raw_s - 40)
                lsum[j] += e;
                f2 e2; e2[0] = e; e2[1] = e;
                #pragma unroll
                for (int hp = 0; hp < 5; ++hp) res2[j][hp] += e2 * vf2[hp];  // v_pk_fma_f32
            }
        }
    }
    __syncthreads();   // all K/V reads done before y overwrites the region

    // ---- phase 5: residual + LayerNorm, write y rows to LDS ----
    float g[9], bb[9];
    #pragma unroll
    for (int d = 0; d < ND; ++d) { g[d] = ln_g[d]; bb[d] = ln_b[d]; }

    #pragma unroll
    for (int j = 0; j < 4; ++j) {
        if (j < qc) {
            float res[9];
            #pragma unroll
            for (int hp = 0; hp < 4; ++hp) {
                res[2 * hp]     = res2[j][hp][0];
                res[2 * hp + 1] = res2[j][hp][1];
            }
            res[8] = res2[j][4][0];

            float rl = __builtin_amdgcn_rcpf(lsum[j]);
            float y[9];
            float s = 0.0f;
            #pragma unroll
            for (int d = 0; d < ND; ++d) {
                y[d] = xr[j][d] + res[d] * rl;
                s += y[d];
            }
            float mu = s * (1.0f / 9.0f);
            float var = 0.0f;
            #pragma unroll
            for (int d = 0; d < ND; ++d) {
                float t = y[d] - mu;
                var += t * t;
            }
            float rs = __builtin_amdgcn_rsqf(var * (1.0f / 9.0f) + 1e-5f);
            float* ydst = (float*)sm + lane * (NQ * ND) + (qs + j) * ND;
            #pragma unroll
            for (int d = 0; d < ND; ++d) ydst[d] = (y[d] - mu) * rs * g[d] + bb[d];
        }
    }
    __syncthreads();

    // ---- phase 6: coalesced nontemporal store of y chunk ----
    {
        const f4* srcs = (const f4*)sm;
        f4* dstg = (f4*)(out + base);
        #pragma unroll
        for (int i = 0; i < 8; ++i) {
            int idx = tid + i * TPB;
            if (idx < X4) __builtin_nontemporal_store(srcs[idx], &dstg[idx]);
        }
    }
}

extern "C" void kernel_launch(void* const* d_in, const int* in_sizes, int n_in,
                              void* d_out, int out_size, void* d_ws, size_t ws_size,
                              hipStream_t stream) {
    const float* x   = (const float*)d_in[0];
    const float* Wjk = (const float*)d_in[1];
    const float* bjk = (const float*)d_in[2];
    const float* Wok = (const float*)d_in[3];
    const float* bok = (const float*)d_in[4];
    const float* Wgk = (const float*)d_in[5];
    const float* bgk = (const float*)d_in[6];
    const float* Wbk = (const float*)d_in[7];
    const float* bbk = (const float*)d_in[8];
    const float* Wjv = (const float*)d_in[9];
    const float* bjv = (const float*)d_in[10];
    const float* Wov = (const float*)d_in[11];
    const float* bov = (const float*)d_in[12];
    const float* Wgv = (const float*)d_in[13];
    const float* bgv = (const float*)d_in[14];
    const float* Wbv = (const float*)d_in[15];
    const float* bbv = (const float*)d_in[16];
    const float* lng = (const float*)d_in[17];
    const float* lnb = (const float*)d_in[18];
    float* out = (float*)d_out;

    const int nbatch = in_sizes[0] / (NQ * ND);      // 262144
    const int nblocks = nbatch / BPB;                // 4096

    hipLaunchKernelGGL(attn_fused, dim3(nblocks), dim3(TPB), 0, stream,
                       x, Wjk, bjk, Wok, bok, Wgk, bgk, Wbk, bbk,
                       Wjv, bjv, Wov, bov, Wgv, bgv, Wbv, bbv, lng, lnb, out);
}